// Round 3
// baseline (802.751 us; speedup 1.0000x reference)
//
#include <hip/hip_runtime.h>
#include <hip/hip_bf16.h>

typedef short short8 __attribute__((ext_vector_type(8)));
typedef float f32x4 __attribute__((ext_vector_type(4)));
typedef float f32x2 __attribute__((ext_vector_type(2)));
typedef unsigned short u16;
typedef unsigned int u32;
typedef u32 u32x4 __attribute__((ext_vector_type(4)));

#define NL_STRIDE 57344
#define OFF_W1F 0
#define OFF_W2F 16384
#define OFF_W3F 49152
#define OFF_W1K 53248
#define OFF_B1  54272
#define OFF_B2  54784
#define OFF_B3  55296

__device__ __forceinline__ u16 f2bf(float f) {
  union { float f; unsigned int u; } v; v.f = f;
  unsigned int r = v.u + 0x7fffu + ((v.u >> 16) & 1u);
  return (u16)(r >> 16);
}

// pack two fp32 -> dword of 2 bf16 (round-half-up): a in low u16, b in high
__device__ __forceinline__ u32 pack_bf16_2(float a, float b) {
  union { float f; u32 u; } x, y; x.f = a; y.f = b;
  u32 ra = x.u + 0x8000u, rb = y.u + 0x8000u;
  return (ra >> 16) | (rb & 0xffff0000u);
}

// GELU pair; polynomial Phi-fit, max |err| ~6e-3 vs exact erf-GELU (preacts |x|<~1.5).
__device__ __forceinline__ f32x2 gelu2(f32x2 x) {
  f32x2 u = x * x;
  f32x2 t = u * 0.00417617f + (-0.0560330f);
  t = t * u + 0.394326f;
  f32x2 s = x * t + 0.5f;
  s.x = __builtin_amdgcn_fmed3f(s.x, 0.0f, 1.0f);
  s.y = __builtin_amdgcn_fmed3f(s.y, 0.0f, 1.0f);
  return x * s;
}

// hid column-pair permutation: lds position p within a 32-block holds logical col
// (p>>1) | ((p&1)<<4)  (so cols c and c+16 sit adjacent -> packed u32 writes).
__device__ __forceinline__ int kperm(int k) {
  int b = k & 31;
  return (k & ~31) | ((b >> 1) | ((b & 1) << 4));
}

// ---------------- prep: swizzle fp32 weights -> bf16 MFMA B-fragment order in ws ----
// B-frag (16x16x32 bf16), tile (kt,nt): lane l holds B[kt*32+(l>>4)*8+j][nt*16+(l&15)],
// flat elem = (kt*NT+nt)*512 + l*8 + j.  W2/W3 K-dims and W1K/B1/B2 vectors are
// kperm-permuted to match the packed hid layout.
__global__ __launch_bounds__(256) void prep_kernel(
    const float* __restrict__ sW1, const float* __restrict__ sb1,
    const float* __restrict__ sW2, const float* __restrict__ sb2,
    const float* __restrict__ sW3, const float* __restrict__ sb3,
    const float* __restrict__ tW1, const float* __restrict__ tb1,
    const float* __restrict__ tW2, const float* __restrict__ tb2,
    const float* __restrict__ tW3, const float* __restrict__ tb3,
    char* __restrict__ ws)
{
  int nl = blockIdx.x;               // 0..7 = layer*2 + net
  int layer = nl >> 1, net = nl & 1;
  const float* W1 = net ? tW1 : sW1;
  const float* W2 = net ? tW2 : sW2;
  const float* W3 = net ? tW3 : sW3;
  const float* B1 = net ? tb1 : sb1;
  const float* B2 = net ? tb2 : sb2;
  const float* B3 = net ? tb3 : sb3;
  char* base = ws + (size_t)nl * NL_STRIDE;
  int e = blockIdx.y * 256 + (int)threadIdx.x;

  if (e < 8192) {                                   // W1 (h-rows 2..65): K=64, N=128
    int kt = e >> 12, rem = e & 4095, nt = rem >> 9, r2 = rem & 511;
    int l = r2 >> 3, j = r2 & 7;
    int k = kt * 32 + (l >> 4) * 8 + j, n = nt * 16 + (l & 15);
    ((u16*)(base + OFF_W1F))[e] = f2bf(W1[layer * 8448 + (2 + k) * 128 + n]);
  } else if (e < 24576) {                           // W2: K=128 (kperm), N=128
    int e2 = e - 8192;
    int kt = e2 >> 12, nt = (e2 >> 9) & 7, l = (e2 >> 3) & 63, j = e2 & 7;
    int k = kt * 32 + (l >> 4) * 8 + j, n = nt * 16 + (l & 15);
    ((u16*)(base + OFF_W2F))[e2] = f2bf(W2[layer * 16384 + kperm(k) * 128 + n]);
  } else if (e < 26624) {                           // W3: K=128 (kperm), N padded 2->16
    int e3 = e - 24576;
    int kt = e3 >> 9, l = (e3 >> 3) & 63, j = e3 & 7;
    int k = kt * 32 + (l >> 4) * 8 + j, n = l & 15;
    float v = (n < 2) ? W3[layer * 256 + kperm(k) * 2 + n] : 0.0f;
    ((u16*)(base + OFF_W3F))[e3] = f2bf(v);
  } else if (e < 26880) {                           // W1 keep-rows 0..1 fp32 [2][128], kperm cols
    int e4 = e - 26624; int r = e4 >> 7, n = e4 & 127;
    ((float*)(base + OFF_W1K))[e4] = W1[layer * 8448 + r * 128 + kperm(n)];
  } else if (e < 27008) {                           // b1, kperm
    int e5 = e - 26880; ((float*)(base + OFF_B1))[e5] = B1[layer * 128 + kperm(e5)];
  } else if (e < 27136) {                           // b2, kperm
    int e6 = e - 27008; ((float*)(base + OFF_B2))[e6] = B2[layer * 128 + kperm(e6)];
  } else if (e < 27138) {
    int e7 = e - 27136; ((float*)(base + OFF_B3))[e7] = B3[layer * 2 + e7];
  }
}

// ---------------- main fused kernel: 128 rows/block, 4 waves, M-split -----------
// wave wv owns rows [wv*32, wv*32+32): mt tiles {2wv, 2wv+1}, all 8 n-tiles.
__global__ __launch_bounds__(256, 4) void realnvp_kernel(
    const float* __restrict__ theta, const float* __restrict__ h_g,
    const char* __restrict__ ws, float* __restrict__ out)
{
  __shared__ __align__(16) u16 hid[128 * 136];   // hidden, bf16, pair-packed cols, stride 136
  __shared__ __align__(16) float x_lds[128 * 4]; // current x, fp32
  __shared__ float sbuf[2 * 128 * 2];            // s/t outputs per net

  const int tid = (int)threadIdx.x;
  const int row0 = (int)blockIdx.x * 128;
  const int wv = tid >> 6, lane = tid & 63, q = lane >> 4, lr = lane & 15;

  // ---- stage theta -> x_lds
  if (tid < 128) {
    float4 t4 = *(const float4*)(theta + (size_t)(row0 + tid) * 4);
    x_lds[tid * 4 + 0] = t4.x; x_lds[tid * 4 + 1] = t4.y;
    x_lds[tid * 4 + 2] = t4.z; x_lds[tid * 4 + 3] = t4.w;
  }

  // ---- h A-fragments -> registers (wave-private rows; persist across all 8 nets)
  short8 hf[2][2];                               // [mt i][kt]
#pragma unroll
  for (int i = 0; i < 2; ++i)
#pragma unroll
    for (int kt = 0; kt < 2; ++kt) {
      const float* src = h_g + (size_t)(row0 + wv * 32 + i * 16 + lr) * 64 + kt * 32 + q * 8;
      float4 f0 = *(const float4*)(src);
      float4 f1 = *(const float4*)(src + 4);
      union { u32x4 u; short8 s; } cv;
      cv.u[0] = pack_bf16_2(f0.x, f0.y);
      cv.u[1] = pack_bf16_2(f0.z, f0.w);
      cv.u[2] = pack_bf16_2(f1.x, f1.y);
      cv.u[3] = pack_bf16_2(f1.z, f1.w);
      hf[i][kt] = cv.s;
    }
  __syncthreads();

  float logdet = 0.0f;
  const f32x4 zero4 = {0.f, 0.f, 0.f, 0.f};
  constexpr int KEEP0[4] = {0, 1, 2, 0}, KEEP1[4] = {1, 2, 3, 3};
  constexpr int TR0[4]   = {2, 0, 0, 1}, TR1[4]   = {3, 3, 1, 2};

#pragma unroll
  for (int layer = 0; layer < 4; ++layer) {
    const int k0 = KEEP0[layer], k1 = KEEP1[layer];

#pragma unroll 1
    for (int net = 0; net < 2; ++net) {
      const char* base = ws + (size_t)(layer * 2 + net) * NL_STRIDE;
      const u16* w1f = (const u16*)(base + OFF_W1F);
      const u16* w2f = (const u16*)(base + OFF_W2F);
      const u16* w3f = (const u16*)(base + OFF_W3F);
      const float* w1k = (const float*)(base + OFF_W1K);
      const float* b1 = (const float*)(base + OFF_B1);
      const float* b2 = (const float*)(base + OFF_B2);
      const float* b3 = (const float*)(base + OFF_B3);

      // ============ GEMM1: acc = h @ W1h  (wave: 32 rows x 128 cols, K=64) =========
      f32x4 acc[2][8];
#pragma unroll
      for (int i = 0; i < 2; ++i)
#pragma unroll
        for (int nt = 0; nt < 8; ++nt) acc[i][nt] = zero4;
#pragma unroll
      for (int kt = 0; kt < 2; ++kt)
#pragma unroll
        for (int a = 0; a < 4; ++a) {
          short8 b0 = *(const short8*)(w1f + (kt * 8 + 2 * a + 0) * 512 + lane * 8);
          short8 b1v = *(const short8*)(w1f + (kt * 8 + 2 * a + 1) * 512 + lane * 8);
#pragma unroll
          for (int i = 0; i < 2; ++i) {
            acc[i][2 * a]     = __builtin_amdgcn_mfma_f32_16x16x32_bf16(hf[i][kt], b0, acc[i][2 * a], 0, 0, 0);
            acc[i][2 * a + 1] = __builtin_amdgcn_mfma_f32_16x16x32_bf16(hf[i][kt], b1v, acc[i][2 * a + 1], 0, 0, 0);
          }
        }
      // epilogue vectors (kperm'd pairs -> float2 loads)
      f32x2 wk0v[4], wk1v[4], bbv[4];
#pragma unroll
      for (int a = 0; a < 4; ++a) {
        wk0v[a] = *(const f32x2*)(w1k + a * 32 + 2 * lr);
        wk1v[a] = *(const f32x2*)(w1k + 128 + a * 32 + 2 * lr);
        bbv[a]  = *(const f32x2*)(b1 + a * 32 + 2 * lr);
      }
      __syncthreads();               // prev net's GEMM3 readers of hid are done
#pragma unroll
      for (int i = 0; i < 2; ++i)
#pragma unroll
        for (int r = 0; r < 4; ++r) {
          int row = wv * 32 + i * 16 + q * 4 + r;
          f32x4 xr = *(const f32x4*)(x_lds + row * 4);
          float xk0 = xr[k0], xk1 = xr[k1];
          u32* wrow = (u32*)&hid[row * 136];
#pragma unroll
          for (int a = 0; a < 4; ++a) {
            f32x2 v = {acc[i][2 * a][r], acc[i][2 * a + 1][r]};
            v = wk0v[a] * xk0 + v;
            v = wk1v[a] * xk1 + v;
            v = v + bbv[a];
            f32x2 g = gelu2(v);
            wrow[a * 16 + lr] = pack_bf16_2(g.x, g.y);
          }
        }
      __syncthreads();

      // ============ GEMM2: acc2 = gelu1 @ W2p  (K=128, hid in-place) ===============
      f32x4 acc2[2][8];
#pragma unroll
      for (int i = 0; i < 2; ++i)
#pragma unroll
        for (int nt = 0; nt < 8; ++nt) acc2[i][nt] = zero4;
#pragma unroll
      for (int kt = 0; kt < 4; ++kt) {
        short8 a0 = *(const short8*)(&hid[(wv * 32 + lr) * 136 + kt * 32 + q * 8]);
        short8 a1 = *(const short8*)(&hid[(wv * 32 + 16 + lr) * 136 + kt * 32 + q * 8]);
#pragma unroll
        for (int a = 0; a < 4; ++a) {
          short8 b0 = *(const short8*)(w2f + (kt * 8 + 2 * a + 0) * 512 + lane * 8);
          short8 b1v = *(const short8*)(w2f + (kt * 8 + 2 * a + 1) * 512 + lane * 8);
          acc2[0][2 * a]     = __builtin_amdgcn_mfma_f32_16x16x32_bf16(a0, b0, acc2[0][2 * a], 0, 0, 0);
          acc2[1][2 * a]     = __builtin_amdgcn_mfma_f32_16x16x32_bf16(a1, b0, acc2[1][2 * a], 0, 0, 0);
          acc2[0][2 * a + 1] = __builtin_amdgcn_mfma_f32_16x16x32_bf16(a0, b1v, acc2[0][2 * a + 1], 0, 0, 0);
          acc2[1][2 * a + 1] = __builtin_amdgcn_mfma_f32_16x16x32_bf16(a1, b1v, acc2[1][2 * a + 1], 0, 0, 0);
        }
      }
      f32x2 cbv[4];
#pragma unroll
      for (int a = 0; a < 4; ++a) cbv[a] = *(const f32x2*)(b2 + a * 32 + 2 * lr);
      __syncthreads();               // all GEMM2 reads of hid done before overwrite
#pragma unroll
      for (int i = 0; i < 2; ++i)
#pragma unroll
        for (int r = 0; r < 4; ++r) {
          int row = wv * 32 + i * 16 + q * 4 + r;
          u32* wrow = (u32*)&hid[row * 136];
#pragma unroll
          for (int a = 0; a < 4; ++a) {
            f32x2 v = {acc2[i][2 * a][r], acc2[i][2 * a + 1][r]};
            f32x2 g = gelu2(v + cbv[a]);
            wrow[a * 16 + lr] = pack_bf16_2(g.x, g.y);
          }
        }
      __syncthreads();

      // ============ GEMM3: s/t = gelu2 @ W3p + b3  (N padded to 16) ================
      f32x4 acc3[2]; acc3[0] = zero4; acc3[1] = zero4;
#pragma unroll
      for (int kt = 0; kt < 4; ++kt) {
        short8 b = *(const short8*)(w3f + kt * 512 + lane * 8);
#pragma unroll
        for (int i = 0; i < 2; ++i) {
          short8 a = *(const short8*)(&hid[((wv * 2 + i) * 16 + lr) * 136 + kt * 32 + q * 8]);
          acc3[i] = __builtin_amdgcn_mfma_f32_16x16x32_bf16(a, b, acc3[i], 0, 0, 0);
        }
      }
      if (lr < 2) {
        float bbs = b3[lr];
#pragma unroll
        for (int i = 0; i < 2; ++i) {
          int rb = (wv * 2 + i) * 16 + q * 4;
#pragma unroll
          for (int r = 0; r < 4; ++r)
            sbuf[net * 256 + (rb + r) * 2 + lr] = acc3[i][r] + bbs;
        }
      }
      __syncthreads();
    }  // net

    // ================= coupling update =================
    if (tid < 128) {
      float s0 = sbuf[tid * 2 + 0], s1 = sbuf[tid * 2 + 1];
      float t0 = sbuf[256 + tid * 2 + 0], t1 = sbuf[256 + tid * 2 + 1];
      const int a0 = TR0[layer], a1 = TR1[layer];
      x_lds[tid * 4 + a0] = x_lds[tid * 4 + a0] * __expf(s0) + t0;
      x_lds[tid * 4 + a1] = x_lds[tid * 4 + a1] * __expf(s1) + t1;
      logdet += s0 + s1;
    }
    __syncthreads();
  }  // layer

  if (tid < 128) {
    float x0 = x_lds[tid * 4 + 0], x1 = x_lds[tid * 4 + 1];
    float x2 = x_lds[tid * 4 + 2], x3 = x_lds[tid * 4 + 3];
    out[row0 + tid] = -0.5f * (x0 * x0 + x1 * x1 + x2 * x2 + x3 * x3)
                      - 3.6757541328f + logdet;
  }
}

extern "C" void kernel_launch(void* const* d_in, const int* in_sizes, int n_in,
                              void* d_out, int out_size, void* d_ws, size_t ws_size,
                              hipStream_t stream) {
  (void)in_sizes; (void)n_in; (void)out_size; (void)ws_size;
  const float* theta = (const float*)d_in[0];
  const float* h     = (const float*)d_in[1];
  const float* sW1 = (const float*)d_in[2],  *sb1 = (const float*)d_in[3];
  const float* sW2 = (const float*)d_in[4],  *sb2 = (const float*)d_in[5];
  const float* sW3 = (const float*)d_in[6],  *sb3 = (const float*)d_in[7];
  const float* tW1 = (const float*)d_in[8],  *tb1 = (const float*)d_in[9];
  const float* tW2 = (const float*)d_in[10], *tb2 = (const float*)d_in[11];
  const float* tW3 = (const float*)d_in[12], *tb3 = (const float*)d_in[13];
  float* out = (float*)d_out;
  char* ws = (char*)d_ws;

  dim3 pgrid(8, 107);   // 8 net-layers x ceil(27138/256)
  prep_kernel<<<pgrid, 256, 0, stream>>>(sW1, sb1, sW2, sb2, sW3, sb3,
                                         tW1, tb1, tW2, tb2, tW3, tb3, ws);
  realnvp_kernel<<<4096, 256, 0, stream>>>(theta, h, (const char*)ws, out);
}

// Round 4
// 617.750 us; speedup vs baseline: 1.2995x; 1.2995x over previous
//
#include <hip/hip_runtime.h>
#include <hip/hip_bf16.h>

typedef short short8 __attribute__((ext_vector_type(8)));
typedef float f32x4 __attribute__((ext_vector_type(4)));
typedef float f32x2 __attribute__((ext_vector_type(2)));
typedef unsigned short u16;
typedef unsigned int u32;
typedef u32 u32x4 __attribute__((ext_vector_type(4)));

#define NL_STRIDE 57344
#define OFF_W1F 0
#define OFF_W2F 16384
#define OFF_W3F 49152
#define OFF_W1K 53248
#define OFF_B1  54272
#define OFF_B2  54784
#define OFF_B3  55296

__device__ __forceinline__ u16 f2bf(float f) {
  union { float f; unsigned int u; } v; v.f = f;
  unsigned int r = v.u + 0x7fffu + ((v.u >> 16) & 1u);
  return (u16)(r >> 16);
}

// pack two fp32 -> dword of 2 bf16 (round-half-up): a low, b high
__device__ __forceinline__ u32 pack_bf16_2(float a, float b) {
  union { float f; u32 u; } x, y; x.f = a; y.f = b;
  u32 ra = x.u + 0x8000u, rb = y.u + 0x8000u;
  return (ra >> 16) | (rb & 0xffff0000u);
}

// GELU pair; polynomial Phi-fit, max |err| ~6e-3 vs exact erf-GELU.
__device__ __forceinline__ f32x2 gelu2(f32x2 x) {
  f32x2 u = x * x;
  f32x2 t = u * 0.00417617f + (-0.0560330f);
  t = t * u + 0.394326f;
  f32x2 s = x * t + 0.5f;
  s.x = __builtin_amdgcn_fmed3f(s.x, 0.0f, 1.0f);
  s.y = __builtin_amdgcn_fmed3f(s.y, 0.0f, 1.0f);
  return x * s;
}

// hid column-pair permutation: lds position p within a 32-block holds logical col
// (p>>1) | ((p&1)<<4)  (cols c and c+16 adjacent -> packed u32 epilogue writes).
__device__ __forceinline__ int kperm(int k) {
  int b = k & 31;
  return (k & ~31) | ((b >> 1) | ((b & 1) << 4));
}

// ---------------- prep: swizzle fp32 weights -> bf16 MFMA B-fragment order in ws ----
// B-frag (16x16x32 bf16), tile (kt,nt): lane l holds B[kt*32+(l>>4)*8+j][nt*16+(l&15)],
// flat elem = (kt*NT+nt)*512 + l*8 + j.  W2/W3 K-dims and W1K/B1/B2 are kperm'd.
__global__ __launch_bounds__(256) void prep_kernel(
    const float* __restrict__ sW1, const float* __restrict__ sb1,
    const float* __restrict__ sW2, const float* __restrict__ sb2,
    const float* __restrict__ sW3, const float* __restrict__ sb3,
    const float* __restrict__ tW1, const float* __restrict__ tb1,
    const float* __restrict__ tW2, const float* __restrict__ tb2,
    const float* __restrict__ tW3, const float* __restrict__ tb3,
    char* __restrict__ ws)
{
  int nl = blockIdx.x;               // 0..7 = layer*2 + net
  int layer = nl >> 1, net = nl & 1;
  const float* W1 = net ? tW1 : sW1;
  const float* W2 = net ? tW2 : sW2;
  const float* W3 = net ? tW3 : sW3;
  const float* B1 = net ? tb1 : sb1;
  const float* B2 = net ? tb2 : sb2;
  const float* B3 = net ? tb3 : sb3;
  char* base = ws + (size_t)nl * NL_STRIDE;
  int e = blockIdx.y * 256 + (int)threadIdx.x;

  if (e < 8192) {                                   // W1 (h-rows 2..65): K=64, N=128
    int kt = e >> 12, rem = e & 4095, nt = rem >> 9, r2 = rem & 511;
    int l = r2 >> 3, j = r2 & 7;
    int k = kt * 32 + (l >> 4) * 8 + j, n = nt * 16 + (l & 15);
    ((u16*)(base + OFF_W1F))[e] = f2bf(W1[layer * 8448 + (2 + k) * 128 + n]);
  } else if (e < 24576) {                           // W2: K=128 (kperm), N=128
    int e2 = e - 8192;
    int kt = e2 >> 12, nt = (e2 >> 9) & 7, l = (e2 >> 3) & 63, j = e2 & 7;
    int k = kt * 32 + (l >> 4) * 8 + j, n = nt * 16 + (l & 15);
    ((u16*)(base + OFF_W2F))[e2] = f2bf(W2[layer * 16384 + kperm(k) * 128 + n]);
  } else if (e < 26624) {                           // W3: K=128 (kperm), N padded 2->16
    int e3 = e - 24576;
    int kt = e3 >> 9, l = (e3 >> 3) & 63, j = e3 & 7;
    int k = kt * 32 + (l >> 4) * 8 + j, n = l & 15;
    float v = (n < 2) ? W3[layer * 256 + kperm(k) * 2 + n] : 0.0f;
    ((u16*)(base + OFF_W3F))[e3] = f2bf(v);
  } else if (e < 26880) {                           // W1 keep-rows 0..1 fp32 [2][128], kperm cols
    int e4 = e - 26624; int r = e4 >> 7, n = e4 & 127;
    ((float*)(base + OFF_W1K))[e4] = W1[layer * 8448 + r * 128 + kperm(n)];
  } else if (e < 27008) {                           // b1, kperm
    int e5 = e - 26880; ((float*)(base + OFF_B1))[e5] = B1[layer * 128 + kperm(e5)];
  } else if (e < 27136) {                           // b2, kperm
    int e6 = e - 27008; ((float*)(base + OFF_B2))[e6] = B2[layer * 128 + kperm(e6)];
  } else if (e < 27138) {
    int e7 = e - 27136; ((float*)(base + OFF_B3))[e7] = B3[layer * 2 + e7];
  }
}

// ---------------- main fused kernel: 128 rows/block, 512 threads (8 waves) ----------
// wave grid 2x4: mh = wave&1 owns rows [64*mh,64*mh+64) (mt 4mh..4mh+3);
// nq = wave>>1 owns n-tile pair {2nq,2nq+1} = logical cols {32nq+c, 32nq+16+c}.
__global__ __launch_bounds__(512, 4) void realnvp_kernel(
    const float* __restrict__ theta, const float* __restrict__ h_g,
    const char* __restrict__ ws, float* __restrict__ out)
{
  __shared__ __align__(16) u16 hs[128 * 72];     // h tile, bf16, stride 72
  __shared__ __align__(16) u16 hid[128 * 136];   // hidden, bf16, pair-packed cols, stride 136
  __shared__ __align__(16) float x_lds[128 * 4]; // current x, fp32
  __shared__ float sbuf[2 * 128 * 2];            // s/t outputs per net

  const int tid = (int)threadIdx.x;
  const int row0 = (int)blockIdx.x * 128;
  const int wave = tid >> 6, lane = tid & 63, q = lane >> 4, lr = lane & 15;
  const int mh = wave & 1, nq = wave >> 1;

  // ---- stage theta -> x_lds
  if (tid < 128) {
    float4 t4 = *(const float4*)(theta + (size_t)(row0 + tid) * 4);
    x_lds[tid * 4 + 0] = t4.x; x_lds[tid * 4 + 1] = t4.y;
    x_lds[tid * 4 + 2] = t4.z; x_lds[tid * 4 + 3] = t4.w;
  }
  // ---- stage h -> hs (bf16); thread covers 16 cols of one row
  {
    int r = tid >> 2, sg = tid & 3;
    const float* src = h_g + (size_t)(row0 + r) * 64 + sg * 16;
    u16* dst = &hs[r * 72 + sg * 16];
#pragma unroll
    for (int c = 0; c < 16; c += 8) {
      float4 f0 = *(const float4*)(src + c);
      float4 f1 = *(const float4*)(src + c + 4);
      u32x4 o;
      o[0] = pack_bf16_2(f0.x, f0.y);
      o[1] = pack_bf16_2(f0.z, f0.w);
      o[2] = pack_bf16_2(f1.x, f1.y);
      o[3] = pack_bf16_2(f1.z, f1.w);
      *(u32x4*)(dst + c) = o;
    }
  }
  __syncthreads();

  float logdet = 0.0f;
  const f32x4 zero4 = {0.f, 0.f, 0.f, 0.f};

#pragma unroll 1
  for (int layer = 0; layer < 4; ++layer) {
    const int k0 = (0x0210 >> (layer * 4)) & 15;   // KEEP[layer][0]
    const int k1 = (0x3321 >> (layer * 4)) & 15;   // KEEP[layer][1]

#pragma unroll 1
    for (int net = 0; net < 2; ++net) {
      const char* base = ws + (size_t)(layer * 2 + net) * NL_STRIDE;
      const u16* w1f = (const u16*)(base + OFF_W1F);
      const u16* w2f = (const u16*)(base + OFF_W2F);
      const u16* w3f = (const u16*)(base + OFF_W3F);
      const float* w1k = (const float*)(base + OFF_W1K);
      const float* b1 = (const float*)(base + OFF_B1);
      const float* b2 = (const float*)(base + OFF_B2);
      const float* b3 = (const float*)(base + OFF_B3);

      // ============ GEMM1: acc = h @ W1h  (wave: 64 rows x 32 cols, K=64) ==========
      f32x4 acc[4][2];
#pragma unroll
      for (int i = 0; i < 4; ++i) { acc[i][0] = zero4; acc[i][1] = zero4; }
      {
        // all 4 B-frags up front (global, stay in flight over the A ds_reads)
        short8 b00 = *(const short8*)(w1f + (0 * 8 + 2 * nq + 0) * 512 + lane * 8);
        short8 b01 = *(const short8*)(w1f + (0 * 8 + 2 * nq + 1) * 512 + lane * 8);
        short8 b10 = *(const short8*)(w1f + (1 * 8 + 2 * nq + 0) * 512 + lane * 8);
        short8 b11 = *(const short8*)(w1f + (1 * 8 + 2 * nq + 1) * 512 + lane * 8);
        const u16* abase = &hs[(64 * mh + lr) * 72 + q * 8];
#pragma unroll
        for (int kt = 0; kt < 2; ++kt) {
          short8 A0 = *(const short8*)(abase + 0 * (16 * 72) + kt * 32);
          short8 A1 = *(const short8*)(abase + 1 * (16 * 72) + kt * 32);
          short8 A2 = *(const short8*)(abase + 2 * (16 * 72) + kt * 32);
          short8 A3 = *(const short8*)(abase + 3 * (16 * 72) + kt * 32);
          short8 b0 = kt ? b10 : b00, b1v = kt ? b11 : b01;
          acc[0][0] = __builtin_amdgcn_mfma_f32_16x16x32_bf16(A0, b0, acc[0][0], 0, 0, 0);
          acc[1][0] = __builtin_amdgcn_mfma_f32_16x16x32_bf16(A1, b0, acc[1][0], 0, 0, 0);
          acc[2][0] = __builtin_amdgcn_mfma_f32_16x16x32_bf16(A2, b0, acc[2][0], 0, 0, 0);
          acc[3][0] = __builtin_amdgcn_mfma_f32_16x16x32_bf16(A3, b0, acc[3][0], 0, 0, 0);
          acc[0][1] = __builtin_amdgcn_mfma_f32_16x16x32_bf16(A0, b1v, acc[0][1], 0, 0, 0);
          acc[1][1] = __builtin_amdgcn_mfma_f32_16x16x32_bf16(A1, b1v, acc[1][1], 0, 0, 0);
          acc[2][1] = __builtin_amdgcn_mfma_f32_16x16x32_bf16(A2, b1v, acc[2][1], 0, 0, 0);
          acc[3][1] = __builtin_amdgcn_mfma_f32_16x16x32_bf16(A3, b1v, acc[3][1], 0, 0, 0);
        }
      }
      // epilogue1: rank-2 keep-cols + bias + GELU + packed write
      f32x2 wk0 = *(const f32x2*)(w1k + nq * 32 + 2 * lr);
      f32x2 wk1 = *(const f32x2*)(w1k + 128 + nq * 32 + 2 * lr);
      f32x2 bb  = *(const f32x2*)(b1 + nq * 32 + 2 * lr);
      // (prev net's GEMM3 hid readers finished at end-of-net barrier)
#pragma unroll
      for (int i = 0; i < 4; ++i)
#pragma unroll
        for (int r = 0; r < 4; ++r) {
          int row = 64 * mh + 16 * i + q * 4 + r;
          float xk0 = x_lds[row * 4 + k0], xk1 = x_lds[row * 4 + k1];
          f32x2 v = {acc[i][0][r], acc[i][1][r]};
          v = wk0 * xk0 + v;
          v = wk1 * xk1 + v;
          v = v + bb;
          f32x2 g = gelu2(v);
          ((u32*)&hid[row * 136])[nq * 16 + lr] = pack_bf16_2(g.x, g.y);
        }
      __syncthreads();   // S1: hid(gelu1) ready

      // ============ GEMM2: acc2 = gelu1 @ W2p  (K=128) =============================
      f32x4 acc2[4][2];
#pragma unroll
      for (int i = 0; i < 4; ++i) { acc2[i][0] = zero4; acc2[i][1] = zero4; }
      {
        const u16* hbase = &hid[(64 * mh + lr) * 136 + q * 8];
        // B prefetch: keep 2 kt-steps of global loads in flight
        short8 nb0 = *(const short8*)(w2f + (0 * 8 + 2 * nq + 0) * 512 + lane * 8);
        short8 nb1 = *(const short8*)(w2f + (0 * 8 + 2 * nq + 1) * 512 + lane * 8);
        short8 pb0 = *(const short8*)(w2f + (1 * 8 + 2 * nq + 0) * 512 + lane * 8);
        short8 pb1 = *(const short8*)(w2f + (1 * 8 + 2 * nq + 1) * 512 + lane * 8);
#pragma unroll
        for (int kt = 0; kt < 4; ++kt) {
          short8 b0 = nb0, b1v = nb1;
          nb0 = pb0; nb1 = pb1;
          if (kt < 2) {
            pb0 = *(const short8*)(w2f + ((kt + 2) * 8 + 2 * nq + 0) * 512 + lane * 8);
            pb1 = *(const short8*)(w2f + ((kt + 2) * 8 + 2 * nq + 1) * 512 + lane * 8);
          }
          short8 A0 = *(const short8*)(hbase + 0 * (16 * 136) + kt * 32);
          short8 A1 = *(const short8*)(hbase + 1 * (16 * 136) + kt * 32);
          short8 A2 = *(const short8*)(hbase + 2 * (16 * 136) + kt * 32);
          short8 A3 = *(const short8*)(hbase + 3 * (16 * 136) + kt * 32);
          acc2[0][0] = __builtin_amdgcn_mfma_f32_16x16x32_bf16(A0, b0, acc2[0][0], 0, 0, 0);
          acc2[1][0] = __builtin_amdgcn_mfma_f32_16x16x32_bf16(A1, b0, acc2[1][0], 0, 0, 0);
          acc2[2][0] = __builtin_amdgcn_mfma_f32_16x16x32_bf16(A2, b0, acc2[2][0], 0, 0, 0);
          acc2[3][0] = __builtin_amdgcn_mfma_f32_16x16x32_bf16(A3, b0, acc2[3][0], 0, 0, 0);
          acc2[0][1] = __builtin_amdgcn_mfma_f32_16x16x32_bf16(A0, b1v, acc2[0][1], 0, 0, 0);
          acc2[1][1] = __builtin_amdgcn_mfma_f32_16x16x32_bf16(A1, b1v, acc2[1][1], 0, 0, 0);
          acc2[2][1] = __builtin_amdgcn_mfma_f32_16x16x32_bf16(A2, b1v, acc2[2][1], 0, 0, 0);
          acc2[3][1] = __builtin_amdgcn_mfma_f32_16x16x32_bf16(A3, b1v, acc2[3][1], 0, 0, 0);
        }
      }
      f32x2 cb = *(const f32x2*)(b2 + nq * 32 + 2 * lr);
      __syncthreads();   // S2: all GEMM2 reads of hid done (in-place hazard)
#pragma unroll
      for (int i = 0; i < 4; ++i)
#pragma unroll
        for (int r = 0; r < 4; ++r) {
          int row = 64 * mh + 16 * i + q * 4 + r;
          f32x2 v = {acc2[i][0][r], acc2[i][1][r]};
          f32x2 g = gelu2(v + cb);
          ((u32*)&hid[row * 136])[nq * 16 + lr] = pack_bf16_2(g.x, g.y);
        }
      __syncthreads();   // S3: hid(gelu2) ready

      // ============ GEMM3: s/t = gelu2 @ W3p + b3 (wave -> its 16 rows) ============
      f32x4 acc3 = zero4;
      {
        const u16* hbase3 = &hid[(16 * wave + lr) * 136 + q * 8];
#pragma unroll
        for (int kt = 0; kt < 4; ++kt) {
          short8 b = *(const short8*)(w3f + kt * 512 + lane * 8);
          short8 a = *(const short8*)(hbase3 + kt * 32);
          acc3 = __builtin_amdgcn_mfma_f32_16x16x32_bf16(a, b, acc3, 0, 0, 0);
        }
      }
      if (lr < 2) {
        float bbs = b3[lr];
        int rb = 16 * wave + q * 4;
#pragma unroll
        for (int r = 0; r < 4; ++r)
          sbuf[net * 256 + (rb + r) * 2 + lr] = acc3[r] + bbs;
      }
      __syncthreads();   // S4: sbuf ready, hid reads done
    }  // net

    // ================= coupling update =================
    if (tid < 128) {
      float s0 = sbuf[tid * 2 + 0], s1 = sbuf[tid * 2 + 1];
      float t0 = sbuf[256 + tid * 2 + 0], t1 = sbuf[256 + tid * 2 + 1];
      const int a0 = (0x1002 >> (layer * 4)) & 15;   // TRANS[layer][0]
      const int a1 = (0x2133 >> (layer * 4)) & 15;   // TRANS[layer][1]
      x_lds[tid * 4 + a0] = x_lds[tid * 4 + a0] * __expf(s0) + t0;
      x_lds[tid * 4 + a1] = x_lds[tid * 4 + a1] * __expf(s1) + t1;
      logdet += s0 + s1;
    }
    __syncthreads();
  }  // layer

  if (tid < 128) {
    float x0 = x_lds[tid * 4 + 0], x1 = x_lds[tid * 4 + 1];
    float x2 = x_lds[tid * 4 + 2], x3 = x_lds[tid * 4 + 3];
    out[row0 + tid] = -0.5f * (x0 * x0 + x1 * x1 + x2 * x2 + x3 * x3)
                      - 3.6757541328f + logdet;
  }
}

extern "C" void kernel_launch(void* const* d_in, const int* in_sizes, int n_in,
                              void* d_out, int out_size, void* d_ws, size_t ws_size,
                              hipStream_t stream) {
  (void)in_sizes; (void)n_in; (void)out_size; (void)ws_size;
  const float* theta = (const float*)d_in[0];
  const float* h     = (const float*)d_in[1];
  const float* sW1 = (const float*)d_in[2],  *sb1 = (const float*)d_in[3];
  const float* sW2 = (const float*)d_in[4],  *sb2 = (const float*)d_in[5];
  const float* sW3 = (const float*)d_in[6],  *sb3 = (const float*)d_in[7];
  const float* tW1 = (const float*)d_in[8],  *tb1 = (const float*)d_in[9];
  const float* tW2 = (const float*)d_in[10], *tb2 = (const float*)d_in[11];
  const float* tW3 = (const float*)d_in[12], *tb3 = (const float*)d_in[13];
  float* out = (float*)d_out;
  char* ws = (char*)d_ws;

  dim3 pgrid(8, 107);   // 8 net-layers x ceil(27138/256)
  prep_kernel<<<pgrid, 256, 0, stream>>>(sW1, sb1, sW2, sb2, sW3, sb3,
                                         tW1, tb1, tW2, tb2, tW3, tb3, ws);
  realnvp_kernel<<<4096, 512, 0, stream>>>(theta, h, (const char*)ws, out);
}